// Round 10
// baseline (247.920 us; speedup 1.0000x reference)
//
#include <hip/hip_runtime.h>
#include <hip/hip_bf16.h>

typedef __attribute__((ext_vector_type(8))) short bf16x8;
typedef __attribute__((ext_vector_type(4))) float f32x4;
typedef __attribute__((ext_vector_type(16))) float f32x16;
typedef __attribute__((ext_vector_type(4))) unsigned int u32x4;

#define NH 16
#define DM 1024
#define HD 64
#define CSEQ 2048
#define MROWS 8192   // B*C
#define NBH 64       // B*NH

static __device__ __forceinline__ unsigned short f2bf(float f) {
  __hip_bfloat16 h = __float2bfloat16(f);
  return *reinterpret_cast<unsigned short*>(&h);
}

static __device__ __forceinline__ short bf_qscale(short s) {
  // fold attn scale (1/8) and log2(e) into Q: S*0.125*1.4427 -> exp2 domain
  unsigned u = ((unsigned)(unsigned short)s) << 16;
  float f = __builtin_bit_cast(float, u) * 0.18033688f;
  return (short)f2bf(f);
}

static __device__ __forceinline__ void gload_lds16(const void* g, void* l) {
  __builtin_amdgcn_global_load_lds(
      (const __attribute__((address_space(1))) unsigned int*)g,
      (__attribute__((address_space(3))) unsigned int*)l, 16, 0, 0);
}

// ---------------- cast fp32 -> bf16 (vectorized x4) ----------------
__global__ __launch_bounds__(256) void cast_f32_bf16(const float* __restrict__ in,
                                                     unsigned short* __restrict__ out,
                                                     int n4) {
  int stride = gridDim.x * blockDim.x;
  for (int i = blockIdx.x * blockDim.x + threadIdx.x; i < n4; i += stride) {
    float4 v = ((const float4*)in)[i];
    ushort4 o;
    o.x = f2bf(v.x); o.y = f2bf(v.y); o.z = f2bf(v.z); o.w = f2bf(v.w);
    ((ushort4*)out)[i] = o;
  }
}

// ---------------- transpose + cast: src[K][N] fp32 -> dst[N][K] bf16 ----------------
__global__ __launch_bounds__(256) void transpose_cast(const float* __restrict__ src,
                                                      unsigned short* __restrict__ dst,
                                                      int K, int N) {
  __shared__ float tile[32][33];
  int tx = threadIdx.x, ty = threadIdx.y;
  int n0 = blockIdx.x * 32, k0 = blockIdx.y * 32;
  #pragma unroll
  for (int i = 0; i < 32; i += 8)
    tile[ty + i][tx] = src[(size_t)(k0 + ty + i) * N + n0 + tx];
  __syncthreads();
  #pragma unroll
  for (int i = 0; i < 32; i += 8)
    dst[(size_t)(n0 + ty + i) * K + k0 + tx] = f2bf(tile[tx][ty + i]);
}

// ---------------- shared helpers ----------------
template<int CNT>
static __device__ __forceinline__ void ld_frags(const char* base, int r0, int cx, int g,
                                                bf16x8 (*out)[2]) {
  #pragma unroll
  for (int i = 0; i < CNT; i++) {
    int row = r0 + i * 16 + cx;
    #pragma unroll
    for (int kc = 0; kc < 2; kc++)
      out[i][kc] = *(const bf16x8*)(base + row * 128 + ((((kc << 2) | g) ^ (row & 7)) << 4));
  }
}

#define BARR() __builtin_amdgcn_s_barrier()
#define LGKM0() asm volatile("s_waitcnt lgkmcnt(0)" ::: "memory")
#define VMCNT8() asm volatile("s_waitcnt vmcnt(8)" ::: "memory")
#define VMCNT0() asm volatile("s_waitcnt vmcnt(0)" ::: "memory")
#define PRIO1() __builtin_amdgcn_s_setprio(1)
#define PRIO0() __builtin_amdgcn_s_setprio(0)

// ===================== 128x128 bf16 GEMM, 2 blocks/CU, 2 barriers/tile =====================
// R9-verified (83.7us QKV, MfmaUtil 25%).  reads -> lgkm0 -> BARR (buffer dead)
// -> stage t+2 into it -> 32 MFMA -> vmcnt(8) -> BARR.
// MODE 0: write fp32 out[M][N].
// MODE 1: scatter bf16 into Q,K [bh][cq][d]; V transposed (NO kappa: the 32x32
// attn PV B-frag consumes kv in natural order).
static __device__ __forceinline__ void mfma_all(const bf16x8 af[4][2], const bf16x8 bfr[4][2],
                                                f32x4 acc[4][4]) {
  #pragma unroll
  for (int kc = 0; kc < 2; kc++)
    #pragma unroll
    for (int mi = 0; mi < 4; mi++)
      #pragma unroll
      for (int ni = 0; ni < 4; ni++)
        acc[mi][ni] = __builtin_amdgcn_mfma_f32_16x16x32_bf16(
            af[mi][kc], bfr[ni][kc], acc[mi][ni], 0, 0, 0);
}

template<int MODE>
__global__ __launch_bounds__(256, 2) void gemm128d(const unsigned short* __restrict__ A,
                                                   const unsigned short* __restrict__ BT,
                                                   const float* __restrict__ bias,
                                                   float* __restrict__ outF,
                                                   unsigned short* __restrict__ outQKV,
                                                   int N, int K) {
  __shared__ char sA[2][16384];   // [128 rows][64 k] bf16, rows 128B, slot^(row&7) swizzle
  __shared__ char sB[2][16384];
  int tid = threadIdx.x;
  int w = tid >> 6, l = tid & 63, g = l >> 4, cx = l & 15;
  int wm = (w >> 1) * 64, wn = (w & 1) * 64;

  // XCD-aware bijective swizzle (nwg % 8 == 0: 1536 and 512)
  int nwgx = gridDim.x;
  int nwg = nwgx * gridDim.y;
  int gid = blockIdx.y * nwgx + blockIdx.x;
  int swz = (gid & 7) * (nwg >> 3) + (gid >> 3);
  int bm = (swz / nwgx) * 128, bn = (swz % nwgx) * 128;

  const unsigned short* Ap[4];
  const unsigned short* Bp[4];
  #pragma unroll
  for (int i = 0; i < 4; i++) {
    int c = tid + i * 256;
    int ar = c >> 3, as = ((c & 7) ^ (ar & 7)) * 8;
    Ap[i] = A + (size_t)(bm + ar) * K + as;
    Bp[i] = BT + (size_t)(bn + ar) * K + as;
  }

  #define STAGE_AB(t, buf) do { int ko_ = (t) << 6;                 \
      gload_lds16(Ap[0] + ko_, sA[buf] + (tid)       * 16);         \
      gload_lds16(Ap[1] + ko_, sA[buf] + (tid + 256) * 16);         \
      gload_lds16(Ap[2] + ko_, sA[buf] + (tid + 512) * 16);         \
      gload_lds16(Ap[3] + ko_, sA[buf] + (tid + 768) * 16);         \
      gload_lds16(Bp[0] + ko_, sB[buf] + (tid)       * 16);         \
      gload_lds16(Bp[1] + ko_, sB[buf] + (tid + 256) * 16);         \
      gload_lds16(Bp[2] + ko_, sB[buf] + (tid + 512) * 16);         \
      gload_lds16(Bp[3] + ko_, sB[buf] + (tid + 768) * 16);         \
    } while (0)

  f32x4 acc[4][4];
  #pragma unroll
  for (int i = 0; i < 4; i++)
    #pragma unroll
    for (int j = 0; j < 4; j++) acc[i][j] = (f32x4){0.f, 0.f, 0.f, 0.f};

  int NT = K >> 6;

  STAGE_AB(0, 0);
  STAGE_AB(1, 1);
  VMCNT8();
  BARR();

  int cur = 0;
  for (int t = 0; t < NT; t++) {
    const char* Ac = sA[cur];
    const char* Bc = sB[cur];
    bool h1 = (t + 1) < NT, h2 = (t + 2) < NT;
    bf16x8 af[4][2], bfr[4][2];

    ld_frags<4>(Ac, wm, cx, g, af);
    ld_frags<4>(Bc, wn, cx, g, bfr);
    LGKM0();
    BARR();   // every wave's frags now in regs -> buffer cur is dead

    if (h2) STAGE_AB(t + 2, cur);

    PRIO1(); mfma_all(af, bfr, acc); PRIO0();

    if (h2)      { VMCNT8(); }
    else if (h1) { VMCNT0(); }
    BARR();
    cur ^= 1;
  }

  #pragma unroll
  for (int mi = 0; mi < 4; mi++) {
    #pragma unroll
    for (int ni = 0; ni < 4; ni++) {
      int col = bn + wn + ni * 16 + cx;
      float bv = bias[col];
      int row0 = bm + wm + mi * 16 + g * 4;
      #pragma unroll
      for (int r = 0; r < 4; r++) {
        float v = acc[mi][ni][r] + bv;
        int rr = row0 + r;
        if (MODE == 0) {
          outF[(size_t)rr * N + col] = v;
        } else {
          int which = col >> 10, rem = col & 1023;
          int h = rem >> 6, d = rem & 63;
          int b = rr >> 11, cq = rr & 2047;
          if (which == 2) {
            // V: store transposed, natural kv order (32x32 PV consumes contiguously)
            outQKV[((size_t)2 * NBH + b * NH + h) * (CSEQ * HD) +
                   (size_t)d * CSEQ + cq] = f2bf(v);
          } else {
            outQKV[((size_t)which * NBH + b * NH + h) * (CSEQ * HD) + (size_t)cq * HD + d] = f2bf(v);
          }
        }
      }
    }
  }
  #undef STAGE_AB
}

// ---------------- flash attention (causal), 32x32 MFMA, swapped-QK^T ----------------
// 8 waves x 32 q-rows (QBLK=256), KVBLK=128 in two 64-kv halves.  32x32x16 MFMA
// reads 0.125 B/MAC from LDS (2x better than 16x16x32): per wave per tile still
// 32 ds_read_b128 but covering 32 q -> LDS traffic per q HALVED at unchanged
// occupancy (512 thr, 64KB LDS, <=128 VGPR -> 2 blocks/CU = 4 waves/SIMD).
// S^T C/D: col=lane&31=q (lane-local softmax: tree over 32 regs + 1 shfl_xor(32)),
// row=kv=(e&3)+8*(e>>2)+4*(lane>>5).  P->A-frag repack: 4 cvt_pk + 4 shfl_xor
// + 4 select per 16-kv step (lane<->lane+32 half-exchange).  O C/D: col=d,
// row=q-in-regs; per-q alpha/linv fetched via 16 shfls (rescale rare: defer-max).
// Grid 512 = 64 bh x 8 qb, R6-proven decode/mask/LPT, 1 exact round.
__global__ __launch_bounds__(512, 4) void attn_kernel(const unsigned short* __restrict__ Qb,
                                                      const unsigned short* __restrict__ Kb,
                                                      const unsigned short* __restrict__ VTb,
                                                      unsigned short* __restrict__ O) {
  __shared__ char sKb[2][16384]; // K [128 kv][64 d] bf16: slot sp of row holds d-slot sp^(row&7)
  __shared__ char sVt[2][16384]; // V^T [64 d][128 kv] bf16: slot sp of row d holds kv-slot sp^(d&7)
  int tid = threadIdx.x;
  int w = tid >> 6, l = tid & 63;
  int hi = l >> 5, lq = l & 31;
  int gid = blockIdx.x;
  int bh = ((gid >> 6) << 3) | (gid & 7);
  int qs = (gid >> 3) & 7;
  int qb = (gid & 256) ? qs : (7 - qs);
  int NKV = 2 * qb + 2;

  const unsigned short* Qp  = Qb  + (size_t)bh * CSEQ * HD;
  const unsigned short* Kp  = Kb  + (size_t)bh * CSEQ * HD;
  const unsigned short* VTp = VTb + (size_t)bh * CSEQ * HD;  // [64 d][2048 kv]

  // Q fragments (B-operand 32x32x16: col=lane&31=q, k=d=ks*16+8*hi+j), exp2-scaled
  int qglob = qb * 256 + w * 32 + lq;
  bf16x8 qf[4];
  #pragma unroll
  for (int ks = 0; ks < 4; ks++) {
    qf[ks] = *(const bf16x8*)(Qp + (size_t)qglob * HD + ks * 16 + hi * 8);
    #pragma unroll
    for (int j = 0; j < 8; j++) qf[ks][j] = bf_qscale(qf[ks][j]);
  }

  f32x16 o[2];
  #pragma unroll
  for (int dt = 0; dt < 2; dt++)
    #pragma unroll
    for (int e = 0; e < 16; e++) o[dt][e] = 0.f;
  float mrow = -INFINITY, lrow = 0.f;

  // staging (identical to proven producer layout): pre-swizzled global src, linear LDS dest
  int c0 = tid, c1 = tid + 512;
  int krow0 = c0 >> 3, ksl0 = (c0 & 7) ^ (krow0 & 7);
  int krow1 = c1 >> 3, ksl1 = (c1 & 7) ^ (krow1 & 7);
  int vd0 = c0 >> 4, vsl0 = (c0 & 15) ^ (vd0 & 7);
  int vd1 = c1 >> 4, vsl1 = (c1 & 15) ^ (vd1 & 7);
  const unsigned short* Ksrc0 = Kp + (size_t)krow0 * HD + ksl0 * 8;   // += kt*8192
  const unsigned short* Ksrc1 = Kp + (size_t)krow1 * HD + ksl1 * 8;
  const unsigned short* Vsrc0 = VTp + (size_t)vd0 * CSEQ + vsl0 * 8;  // += kt*128
  const unsigned short* Vsrc1 = VTp + (size_t)vd1 * CSEQ + vsl1 * 8;

  gload_lds16(Ksrc0, sKb[0] + c0 * 16);
  gload_lds16(Ksrc1, sKb[0] + c1 * 16);
  gload_lds16(Vsrc0, sVt[0] + c0 * 16);
  gload_lds16(Vsrc1, sVt[0] + c1 * 16);
  __syncthreads();
  int cur = 0;

  for (int kt = 0; kt < NKV; kt++) {
    if (kt + 1 < NKV) {
      size_t ko = (size_t)(kt + 1) * 128 * HD;
      size_t vo = (size_t)(kt + 1) * 128;
      gload_lds16(Ksrc0 + ko, sKb[cur ^ 1] + c0 * 16);
      gload_lds16(Ksrc1 + ko, sKb[cur ^ 1] + c1 * 16);
      gload_lds16(Vsrc0 + vo, sVt[cur ^ 1] + c0 * 16);
      gload_lds16(Vsrc1 + vo, sVt[cur ^ 1] + c1 * 16);
    }
    const char* Kc = sKb[cur];
    const char* Vc = sVt[cur];

    #pragma unroll
    for (int h = 0; h < 2; h++) {
      // ---- S^T = K * Q^T over 64 kv: A = K rows (m=kv), B = Q (n=q) ----
      f32x16 sacc[2];
      #pragma unroll
      for (int mt = 0; mt < 2; mt++)
        #pragma unroll
        for (int e = 0; e < 16; e++) sacc[mt][e] = 0.f;
      PRIO1();
      #pragma unroll
      for (int ks = 0; ks < 4; ks++) {
        #pragma unroll
        for (int mt = 0; mt < 2; mt++) {
          int row = h * 64 + mt * 32 + lq;
          bf16x8 kf = *(const bf16x8*)(Kc + row * 128 + ((((ks << 1) | hi) ^ (row & 7)) << 4));
          sacc[mt] = __builtin_amdgcn_mfma_f32_32x32x16_bf16(kf, qf[ks], sacc[mt], 0, 0, 0);
        }
      }
      PRIO0();

      // causal mask (exact, only last two kv-tiles can touch diagonal)
      if (kt >= NKV - 2) {
        #pragma unroll
        for (int mt = 0; mt < 2; mt++)
          #pragma unroll
          for (int e = 0; e < 16; e++) {
            int kvg = kt * 128 + h * 64 + mt * 32 + (e & 3) + 8 * (e >> 2) + 4 * hi;
            if (kvg > qglob) sacc[mt][e] = -INFINITY;
          }
      }

      // lane-local max over 32 regs + partner merge
      float t16[16];
      #pragma unroll
      for (int e = 0; e < 16; e++) t16[e] = fmaxf(sacc[0][e], sacc[1][e]);
      #pragma unroll
      for (int s = 8; s >= 1; s >>= 1)
        #pragma unroll
        for (int i = 0; i < 8; i++) if (i < s) t16[i] = fmaxf(t16[i], t16[i + s]);
      float mx = fmaxf(t16[0], __shfl_xor(t16[0], 32));

      // defer-max (T13)
      if (!__all(mx - mrow <= 8.f)) {
        float mnew = fmaxf(mrow, mx);
        float alpha = __builtin_amdgcn_exp2f(mrow - mnew);
        mrow = mnew;
        lrow *= alpha;
        #pragma unroll
        for (int e = 0; e < 16; e++) {
          float ar = __shfl(alpha, (e & 3) + 8 * (e >> 2) + 4 * hi);
          o[0][e] *= ar;
          o[1][e] *= ar;
        }
      }
      #pragma unroll
      for (int mt = 0; mt < 2; mt++)
        #pragma unroll
        for (int e = 0; e < 16; e++)
          sacc[mt][e] = __builtin_amdgcn_exp2f(sacc[mt][e] - mrow);
      // lane-local partial row-sum (merged with partner once, in epilogue)
      float s16[16];
      #pragma unroll
      for (int e = 0; e < 16; e++) s16[e] = sacc[0][e] + sacc[1][e];
      #pragma unroll
      for (int s = 8; s >= 1; s >>= 1)
        #pragma unroll
        for (int i = 0; i < 8; i++) if (i < s) s16[i] += s16[i + s];
      lrow += s16[0];

      // ---- pack P -> A-frags (lane<->lane+32 half-exchange) + PV ----
      PRIO1();
      #pragma unroll
      for (int mt = 0; mt < 2; mt++) {
        #pragma unroll
        for (int b2 = 0; b2 < 2; b2++) {
          unsigned pA, pB, pC, pD;
          asm("v_cvt_pk_bf16_f32 %0, %1, %2" : "=v"(pA) : "v"(sacc[mt][8 * b2 + 0]), "v"(sacc[mt][8 * b2 + 1]));
          asm("v_cvt_pk_bf16_f32 %0, %1, %2" : "=v"(pB) : "v"(sacc[mt][8 * b2 + 2]), "v"(sacc[mt][8 * b2 + 3]));
          asm("v_cvt_pk_bf16_f32 %0, %1, %2" : "=v"(pC) : "v"(sacc[mt][8 * b2 + 4]), "v"(sacc[mt][8 * b2 + 5]));
          asm("v_cvt_pk_bf16_f32 %0, %1, %2" : "=v"(pD) : "v"(sacc[mt][8 * b2 + 6]), "v"(sacc[mt][8 * b2 + 7]));
          unsigned tA = (unsigned)__shfl_xor((int)pA, 32);
          unsigned tB = (unsigned)__shfl_xor((int)pB, 32);
          unsigned tC = (unsigned)__shfl_xor((int)pC, 32);
          unsigned tD = (unsigned)__shfl_xor((int)pD, 32);
          u32x4 wd;
          wd.x = hi ? tC : pA;   // k elems {0,1} (lo) / {8,9}-sourced (hi)
          wd.y = hi ? tD : pB;
          wd.z = hi ? pC : tA;
          wd.w = hi ? pD : tB;
          bf16x8 pf = __builtin_bit_cast(bf16x8, wd);
          int slotb = h * 8 + mt * 4 + b2 * 2 + hi;
          #pragma unroll
          for (int dt = 0; dt < 2; dt++) {
            int d = dt * 32 + lq;
            bf16x8 vf = *(const bf16x8*)(Vc + ((d * 256 + slotb * 16) ^ ((d & 7) << 4)));
            o[dt] = __builtin_amdgcn_mfma_f32_32x32x16_bf16(pf, vf, o[dt], 0, 0, 0);
          }
        }
      }
      PRIO0();
    }

    if (kt + 1 < NKV) {
      __syncthreads();
      cur ^= 1;
    }
  }

  // epilogue: merge partner partial sums once; per-q linv via shfl
  lrow += __shfl_xor(lrow, 32);
  float linv = 1.0f / lrow;
  int b = bh >> 4, hh = bh & 15;
  #pragma unroll
  for (int e = 0; e < 16; e++) {
    int qloc = (e & 3) + 8 * (e >> 2) + 4 * hi;
    float inv = __shfl(linv, qloc);
    int q = qb * 256 + w * 32 + qloc;
    size_t base = ((size_t)(b * CSEQ + q)) * DM + hh * HD;
    O[base + lq]      = f2bf(o[0][e] * inv);
    O[base + 32 + lq] = f2bf(o[1][e] * inv);
  }
}

// ---------------- launch ----------------
extern "C" void kernel_launch(void* const* d_in, const int* in_sizes, int n_in,
                              void* d_out, int out_size, void* d_ws, size_t ws_size,
                              hipStream_t stream) {
  const float* x    = (const float*)d_in[0];
  const float* Wqkv = (const float*)d_in[1];
  const float* bqkv = (const float*)d_in[2];
  const float* Wo   = (const float*)d_in[3];
  const float* bo   = (const float*)d_in[4];
  float* out = (float*)d_out;

  unsigned short* ws = (unsigned short*)d_ws;
  const size_t XB_OFF    = 0;                     // x bf16 [8192][1024]
  const size_t WQKVT_OFF = 8388608;               // Wqkv^T bf16 [3072][1024]
  const size_t WOT_OFF   = WQKVT_OFF + 3145728;   // Wo^T bf16 [1024][1024]
  const size_t QKV_OFF   = WOT_OFF + 1048576;     // Q,K [bh][k][d]; V^T [bh][d][k]
  const size_t ATT_OFF   = QKV_OFF + 3 * 8388608; // att out bf16 [8192][1024]

  unsigned short* xb    = ws + XB_OFF;
  unsigned short* wqkvT = ws + WQKVT_OFF;
  unsigned short* woT   = ws + WOT_OFF;
  unsigned short* qkv   = ws + QKV_OFF;
  unsigned short* att   = ws + ATT_OFF;

  cast_f32_bf16<<<2048, 256, 0, stream>>>(x, xb, (MROWS * DM) / 4);
  transpose_cast<<<dim3(3 * DM / 32, DM / 32), dim3(32, 8), 0, stream>>>(Wqkv, wqkvT, DM, 3 * DM);
  transpose_cast<<<dim3(DM / 32, DM / 32), dim3(32, 8), 0, stream>>>(Wo, woT, DM, DM);

  // 128x128 tile, 2 blocks/CU: QKV 24x64 = 1536 blocks (3 rounds of 512),
  // proj 8x64 = 512 blocks (1 exact round)
  gemm128d<1><<<dim3(3 * DM / 128, MROWS / 128), 256, 0, stream>>>(
      xb, wqkvT, bqkv, nullptr, qkv, 3 * DM, DM);

  // QBLK=256: 64 bh x 8 qb = 512 blocks, 1 exact round at 2 blocks/CU
  attn_kernel<<<dim3(512), 512, 0, stream>>>(
      qkv, qkv + 8388608, qkv + 16777216, att);

  gemm128d<0><<<dim3(DM / 128, MROWS / 128), 256, 0, stream>>>(
      att, woT, bo, out, nullptr, DM, DM);
}